// Round 3
// baseline (520.474 us; speedup 1.0000x reference)
//
#include <hip/hip_runtime.h>
#include <math.h>

#define CIN  256
#define MEDC 128
#define KOUT 128
#define HWSZ 6400   // 80*80
#define NB   16
#define TP   16     // pixels per block
#define SROW 272    // s_arr row stride in u32 (16 groups * 17)

typedef unsigned int u32;
typedef unsigned long long u64;

// Bit-exact emulation of numpy's SIMD float32 exp (Cephes expf with FMA).
__device__ __forceinline__ float numpy_expf(float x) {
#pragma clang fp contract(off)
    const float q = __builtin_rintf(x * 1.44269504088896341f);
    float r = __builtin_fmaf(q, -0.693359375f, x);
    r = __builtin_fmaf(q, 2.12194440e-4f, r);
    float p = __builtin_fmaf(1.9875691500e-4f, r, 1.3981999507e-3f);
    p = __builtin_fmaf(p, r, 8.3334519073e-3f);
    p = __builtin_fmaf(p, r, 4.1665795894e-2f);
    p = __builtin_fmaf(p, r, 1.6666665459e-1f);
    p = __builtin_fmaf(p, r, 5.0000001201e-1f);
    const float r2 = r * r;
    p = __builtin_fmaf(p, r2, r);
    p = p + 1.0f;
    return __builtin_ldexpf(p, (int)q);
}

__global__ void prep_T(const float* __restrict__ w1, const float* __restrict__ w2,
                       float* __restrict__ w1t, float* __restrict__ w2t) {
    const int c = blockIdx.x;    // 256
    const int m = threadIdx.x;   // 128
    w1t[c * MEDC + m] = w1[m * CIN + c];
    // w2t permuted so channels {q, q+64, q+128, q+192} form one float4:
    // w2t[m][4q + ci] = w2[q + 64*ci][m]
    const int q  = c & 63;
    const int ci = c >> 6;
    w2t[m * CIN + q * 4 + ci] = w2[c * MEDC + m];
}

// ---------- bitonic sort helpers: 256 u64 keys over 16 lanes x 16 regs ----------
// position e = (l16<<4) | r ; ascending sort ; rank (desc) = 255 - e

// intra-lane compare-exchange, compile-time direction bit from r
template<int D, int STAGE>
__device__ __forceinline__ void intra_ct(u64 (&k)[16]) {
#pragma unroll
    for (int r = 0; r < 16; ++r) {
        if (!(r & D)) {
            const bool dsc = (r >> STAGE) & 1;             // compile-time
            const bool sw  = (k[r] > k[r ^ D]) != dsc;
            const u64 x0 = k[r], x1 = k[r ^ D];
            k[r]     = sw ? x1 : x0;
            k[r ^ D] = sw ? x0 : x1;
        }
    }
}

// intra-lane compare-exchange, runtime (lane-uniform) direction
template<int D>
__device__ __forceinline__ void intra_rt(u64 (&k)[16], const bool dsc) {
#pragma unroll
    for (int r = 0; r < 16; ++r) {
        if (!(r & D)) {
            const bool sw = (k[r] > k[r ^ D]) != dsc;
            const u64 x0 = k[r], x1 = k[r ^ D];
            k[r]     = sw ? x1 : x0;
            k[r ^ D] = sw ? x0 : x1;
        }
    }
}

// cross-lane exchange via ds_swizzle (BitMode: offset = (xor<<10)|0x1F)
template<int SWZ>
__device__ __forceinline__ u64 swz64(u64 v) {
    const int lo = __builtin_amdgcn_ds_swizzle((int)(unsigned)v, SWZ);
    const int hi = __builtin_amdgcn_ds_swizzle((int)(unsigned)(v >> 32), SWZ);
    return ((u64)(unsigned)hi << 32) | (u64)(unsigned)lo;
}

template<int M, int SWZ>
__device__ __forceinline__ void cross_rt(u64 (&k)[16], const int l16, const bool dsc) {
    const bool keepmax = ((l16 & M) != 0) != dsc;          // lane-uniform
#pragma unroll
    for (int r = 0; r < 16; ++r) {
        const u64 other = swz64<SWZ>(k[r]);
        const bool gt = k[r] > other;
        k[r] = (gt == keepmax) ? k[r] : other;
    }
}

__global__ __launch_bounds__(256, 4)
void csel_main(const float* __restrict__ x,
               const float* __restrict__ w1t, const float* __restrict__ w2t,
               const float* __restrict__ b1, const float* __restrict__ b2,
               float* __restrict__ out) {
    // xs: x tile (stride 20), later overwritten in-place with prod = x * x_
    __shared__ __align__(16) float xs[CIN * 20];           // 20480 B
    // s_arr: sigmoid bits, [pixel][slot] slot(c)=c+(c>>4); hs aliases it (dead before s writes)
    __shared__ __align__(16) u32 s_arr[TP * SROW];         // 17408 B  (total 37888 -> 4 blk/CU)
    float* hs = (float*)s_arr;                             // [MEDC * 20] = 10240 B

    const int t    = threadIdx.x;
    const int pix0 = blockIdx.x * TP;
    const int b    = pix0 / HWSZ;
    const int hw0  = pix0 % HWSZ;
    const float* xb = x + (size_t)b * CIN * HWSZ + hw0;

    // ---- stage x tile: 256 channels x 16 pixels ----
    {
        const int p  = t & (TP - 1);
        const int c0 = t >> 4;
        #pragma unroll
        for (int i = 0; i < 16; ++i) {
            const int c = c0 + i * 16;
            xs[c * 20 + p] = xb[(size_t)c * HWSZ + p];
        }
    }
    __syncthreads();

    // ---- GEMM1: h[m][p] = sequential fp32 FMA chain over c ascending ----
    const int ml = (t & 63) * 2;
    const int pg = t >> 6;
    float a1[2][4] = {{0.f,0.f,0.f,0.f},{0.f,0.f,0.f,0.f}};

    #pragma unroll 4
    for (int c = 0; c < CIN; ++c) {
        const float2 wv = *(const float2*)&w1t[c * MEDC + ml];
        const float4 xv = *(const float4*)&xs[c * 20 + pg * 4];
        a1[0][0] = fmaf(wv.x, xv.x, a1[0][0]);
        a1[0][1] = fmaf(wv.x, xv.y, a1[0][1]);
        a1[0][2] = fmaf(wv.x, xv.z, a1[0][2]);
        a1[0][3] = fmaf(wv.x, xv.w, a1[0][3]);
        a1[1][0] = fmaf(wv.y, xv.x, a1[1][0]);
        a1[1][1] = fmaf(wv.y, xv.y, a1[1][1]);
        a1[1][2] = fmaf(wv.y, xv.z, a1[1][2]);
        a1[1][3] = fmaf(wv.y, xv.w, a1[1][3]);
    }
    // hs region disjoint from xs; first write to hs this iteration -> no barrier needed here
    #pragma unroll
    for (int i = 0; i < 2; ++i) {
        const float bi = b1[ml + i];
        #pragma unroll
        for (int j = 0; j < 4; ++j)
            hs[(ml + i) * 20 + pg * 4 + j] = a1[i][j] + bi;
    }
    __syncthreads();

    // ---- GEMM2: thread owns channels {q, q+64, q+128, q+192} x pixels {p0..p0+3} ----
    // per m: ONE float4 hs read (wave-broadcast) + ONE coalesced float4 w2t read.
    const int q  = t & 63;
    const int p0 = (t >> 6) * 4;
    float a2[4][4];
    #pragma unroll
    for (int i = 0; i < 4; ++i)
        #pragma unroll
        for (int j = 0; j < 4; ++j) a2[i][j] = 0.f;

    #pragma unroll 2
    for (int m = 0; m < MEDC; ++m) {
        const float4 wv = *(const float4*)&w2t[m * CIN + q * 4];
        const float4 hv = *(const float4*)&hs[m * 20 + p0];
        a2[0][0] = fmaf(wv.x, hv.x, a2[0][0]);
        a2[0][1] = fmaf(wv.x, hv.y, a2[0][1]);
        a2[0][2] = fmaf(wv.x, hv.z, a2[0][2]);
        a2[0][3] = fmaf(wv.x, hv.w, a2[0][3]);
        a2[1][0] = fmaf(wv.y, hv.x, a2[1][0]);
        a2[1][1] = fmaf(wv.y, hv.y, a2[1][1]);
        a2[1][2] = fmaf(wv.y, hv.z, a2[1][2]);
        a2[1][3] = fmaf(wv.y, hv.w, a2[1][3]);
        a2[2][0] = fmaf(wv.z, hv.x, a2[2][0]);
        a2[2][1] = fmaf(wv.z, hv.y, a2[2][1]);
        a2[2][2] = fmaf(wv.z, hv.z, a2[2][2]);
        a2[2][3] = fmaf(wv.z, hv.w, a2[2][3]);
        a2[3][0] = fmaf(wv.w, hv.x, a2[3][0]);
        a2[3][1] = fmaf(wv.w, hv.y, a2[3][1]);
        a2[3][2] = fmaf(wv.w, hv.z, a2[3][2]);
        a2[3][3] = fmaf(wv.w, hv.w, a2[3][3]);
    }
    float xv32[4][4];
    #pragma unroll
    for (int ci = 0; ci < 4; ++ci) {
        const float bi = b2[q + 64 * ci];
        #pragma unroll
        for (int pj = 0; pj < 4; ++pj)
            xv32[ci][pj] = a2[ci][pj] + bi;
    }
    __syncthreads();   // all hs reads complete before s_arr overwrite

    // ---- sigmoid bits -> s_arr; prod = x * x_ in-place over xs ----
    #pragma unroll
    for (int ci = 0; ci < 4; ++ci) {
        const int c    = q + 64 * ci;
        const int slot = c + (c >> 4);
        #pragma unroll
        for (int pj = 0; pj < 4; ++pj) {
#pragma clang fp contract(off)
            const int p2 = p0 + pj;
            const float e  = numpy_expf(-xv32[ci][pj]);
            const float dd = 1.0f + e;
            const float s  = 1.0f / dd;
            s_arr[p2 * SROW + slot] = __float_as_uint(s);
            xs[c * 20 + p2] = xs[c * 20 + p2] * xv32[ci][pj];
        }
    }
    __syncthreads();

    // ---- bitonic sort: pixel group = 16 lanes (wave-local, no barriers) ----
    const int p   = t >> 4;
    const int l16 = t & 15;

    u64 k[16];
    {
        const u32* sp = &s_arr[p * SROW + l16 * 17];   // 16 consecutive u32, conflict-free
        const int cbase = l16 * 16;
        #pragma unroll
        for (int r = 0; r < 16; ++r) {
            const u64 s = (u64)sp[r];
            k[r] = (s << 8) | (u64)(255 - (cbase + r));
        }
    }

    // stages 1..3: compile-time directions, intra-lane
    intra_ct<1, 1>(k);
    intra_ct<2, 2>(k); intra_ct<1, 2>(k);
    intra_ct<4, 3>(k); intra_ct<2, 3>(k); intra_ct<1, 3>(k);
    // stage 4: dir = bit4 of e = l16&1, intra-lane
    {
        const bool dsc = (l16 & 1) != 0;
        intra_rt<8>(k, dsc); intra_rt<4>(k, dsc); intra_rt<2>(k, dsc); intra_rt<1>(k, dsc);
    }
    // stage 5: cross m=1 then intra 8..1
    {
        const bool dsc = ((l16 >> 1) & 1) != 0;
        cross_rt<1, 0x041F>(k, l16, dsc);
        intra_rt<8>(k, dsc); intra_rt<4>(k, dsc); intra_rt<2>(k, dsc); intra_rt<1>(k, dsc);
    }
    // stage 6: cross m=2,1 then intra
    {
        const bool dsc = ((l16 >> 2) & 1) != 0;
        cross_rt<2, 0x081F>(k, l16, dsc);
        cross_rt<1, 0x041F>(k, l16, dsc);
        intra_rt<8>(k, dsc); intra_rt<4>(k, dsc); intra_rt<2>(k, dsc); intra_rt<1>(k, dsc);
    }
    // stage 7: cross m=4,2,1 then intra
    {
        const bool dsc = ((l16 >> 3) & 1) != 0;
        cross_rt<4, 0x101F>(k, l16, dsc);
        cross_rt<2, 0x081F>(k, l16, dsc);
        cross_rt<1, 0x041F>(k, l16, dsc);
        intra_rt<8>(k, dsc); intra_rt<4>(k, dsc); intra_rt<2>(k, dsc); intra_rt<1>(k, dsc);
    }
    // stage 8 (final, ascending): cross m=8,4,2,1 then intra
    {
        cross_rt<8, 0x201F>(k, l16, false);
        cross_rt<4, 0x101F>(k, l16, false);
        cross_rt<2, 0x081F>(k, l16, false);
        cross_rt<1, 0x041F>(k, l16, false);
        intra_rt<8>(k, false); intra_rt<4>(k, false); intra_rt<2>(k, false); intra_rt<1>(k, false);
    }

    // ---- epilogue: positions e=128..255 hold ranks 127..0 ----
    if (l16 >= 8) {
        const int rbase = 255 - l16 * 16;    // rank = rbase - r
        float* ob = out + (size_t)b * KOUT * HWSZ + hw0 + p;
        #pragma unroll
        for (int r = 0; r < 16; ++r) {
            const int c = 255 - (int)(k[r] & 0xFF);
            ob[(size_t)(rbase - r) * HWSZ] = xs[c * 20 + p];
        }
    }
}

extern "C" void kernel_launch(void* const* d_in, const int* in_sizes, int n_in,
                              void* d_out, int out_size, void* d_ws, size_t ws_size,
                              hipStream_t stream) {
    const float* x  = (const float*)d_in[0];
    const float* w1 = (const float*)d_in[1];
    const float* b1 = (const float*)d_in[2];
    const float* w2 = (const float*)d_in[3];
    const float* b2 = (const float*)d_in[4];

    float* w1t = (float*)d_ws;              // 128 KB
    float* w2t = w1t + CIN * MEDC;          // 128 KB

    prep_T<<<CIN, MEDC, 0, stream>>>(w1, w2, w1t, w2t);
    csel_main<<<(NB * HWSZ) / TP, 256, 0, stream>>>(x, w1t, w2t, b1, b2, (float*)d_out);
}

// Round 5
// 436.807 us; speedup vs baseline: 1.1915x; 1.1915x over previous
//
#include <hip/hip_runtime.h>
#include <math.h>

#define CIN  256
#define MEDC 128
#define KOUT 128
#define HWSZ 6400   // 80*80
#define NB   16
#define TP   16     // pixels per block
#define SROW 272    // s_arr row stride in u32 (16 groups * 17)

typedef unsigned int u32;
typedef unsigned long long u64;

// Bit-exact emulation of numpy's SIMD float32 exp (Cephes expf with FMA).
__device__ __forceinline__ float numpy_expf(float x) {
#pragma clang fp contract(off)
    const float q = __builtin_rintf(x * 1.44269504088896341f);
    float r = __builtin_fmaf(q, -0.693359375f, x);
    r = __builtin_fmaf(q, 2.12194440e-4f, r);
    float p = __builtin_fmaf(1.9875691500e-4f, r, 1.3981999507e-3f);
    p = __builtin_fmaf(p, r, 8.3334519073e-3f);
    p = __builtin_fmaf(p, r, 4.1665795894e-2f);
    p = __builtin_fmaf(p, r, 1.6666665459e-1f);
    p = __builtin_fmaf(p, r, 5.0000001201e-1f);
    const float r2 = r * r;
    p = __builtin_fmaf(p, r2, r);
    p = p + 1.0f;
    return __builtin_ldexpf(p, (int)q);
}

__global__ void prep_T(const float* __restrict__ w1, const float* __restrict__ w2,
                       float* __restrict__ w1t, float* __restrict__ w2t) {
    const int c = blockIdx.x;    // 256
    const int m = threadIdx.x;   // 128
    w1t[c * MEDC + m] = w1[m * CIN + c];
    w2t[m * CIN + c]  = w2[c * MEDC + m];
}

// ---------- bitonic sort helpers: 256 u64 keys over 16 lanes x 16 regs ----------
// position e = (l16<<4) | r ; ascending sort ; rank (desc) = 255 - e

template<int D, int STAGE>
__device__ __forceinline__ void intra_ct(u64 (&k)[16]) {
#pragma unroll
    for (int r = 0; r < 16; ++r) {
        if (!(r & D)) {
            const bool dsc = (r >> STAGE) & 1;             // compile-time
            const bool sw  = (k[r] > k[r ^ D]) != dsc;
            const u64 x0 = k[r], x1 = k[r ^ D];
            k[r]     = sw ? x1 : x0;
            k[r ^ D] = sw ? x0 : x1;
        }
    }
}

template<int D>
__device__ __forceinline__ void intra_rt(u64 (&k)[16], const bool dsc) {
#pragma unroll
    for (int r = 0; r < 16; ++r) {
        if (!(r & D)) {
            const bool sw = (k[r] > k[r ^ D]) != dsc;
            const u64 x0 = k[r], x1 = k[r ^ D];
            k[r]     = sw ? x1 : x0;
            k[r ^ D] = sw ? x0 : x1;
        }
    }
}

// cross-lane exchange via ds_swizzle (BitMode: offset = (xor<<10)|0x1F)
template<int SWZ>
__device__ __forceinline__ u64 swz64(u64 v) {
    const int lo = __builtin_amdgcn_ds_swizzle((int)(unsigned)v, SWZ);
    const int hi = __builtin_amdgcn_ds_swizzle((int)(unsigned)(v >> 32), SWZ);
    return ((u64)(unsigned)hi << 32) | (u64)(unsigned)lo;
}

template<int M, int SWZ>
__device__ __forceinline__ void cross_rt(u64 (&k)[16], const int l16, const bool dsc) {
    const bool keepmax = ((l16 & M) != 0) != dsc;          // lane-uniform
#pragma unroll
    for (int r = 0; r < 16; ++r) {
        const u64 other = swz64<SWZ>(k[r]);
        const bool gt = k[r] > other;
        k[r] = (gt == keepmax) ? k[r] : other;
    }
}

__global__ __launch_bounds__(256, 4)
void csel_main(const float* __restrict__ x,
               const float* __restrict__ w1t, const float* __restrict__ w2t,
               const float* __restrict__ b1, const float* __restrict__ b2,
               float* __restrict__ out) {
    // xs: x tile (stride 20), later overwritten in-place with prod = x * x_
    __shared__ __align__(16) float xs[CIN * 20];           // 20480 B
    // s_arr: sigmoid bits, [pixel][slot] slot(c)=c+(c>>4); hs aliases it (dead before s writes)
    __shared__ __align__(16) u32 s_arr[TP * SROW];         // 17408 B  (total 37888 -> 4 blk/CU)
    float* hs = (float*)s_arr;                             // [MEDC * 20] = 10240 B

    const int t    = threadIdx.x;
    const int pix0 = blockIdx.x * TP;
    const int b    = pix0 / HWSZ;
    const int hw0  = pix0 % HWSZ;
    const float* xb = x + (size_t)b * CIN * HWSZ + hw0;

    // ---- stage x tile: 256 channels x 16 pixels ----
    {
        const int p  = t & (TP - 1);
        const int c0 = t >> 4;
        #pragma unroll
        for (int i = 0; i < 16; ++i) {
            const int c = c0 + i * 16;
            xs[c * 20 + p] = xb[(size_t)c * HWSZ + p];
        }
    }
    __syncthreads();

    // ---- GEMM1: h[m][p], sequential fp32 FMA chain over c ascending ----
    // Weights software-pipelined: 16-deep register chunks, double-buffered.
    const int ml = (t & 63) * 2;
    const int pg = t >> 6;
    const float b1a = b1[ml];        // hoisted; latency hides under GEMM1
    const float b1b = b1[ml + 1];
    float a1[2][4] = {{0.f,0.f,0.f,0.f},{0.f,0.f,0.f,0.f}};

    float2 wb[2][16];
    #pragma unroll
    for (int k = 0; k < 16; ++k)
        wb[0][k] = *(const float2*)&w1t[k * MEDC + ml];

    #pragma unroll
    for (int ch = 0; ch < 16; ++ch) {
        const int cur = ch & 1;                            // compile-time after unroll
        if (ch < 15) {
            #pragma unroll
            for (int k = 0; k < 16; ++k)
                wb[cur ^ 1][k] = *(const float2*)&w1t[((ch + 1) * 16 + k) * MEDC + ml];
        }
        #pragma unroll
        for (int k = 0; k < 16; ++k) {
            const int c = ch * 16 + k;
            const float4 xv = *(const float4*)&xs[c * 20 + pg * 4];   // wave-uniform broadcast
            const float2 wv = wb[cur][k];
            a1[0][0] = fmaf(wv.x, xv.x, a1[0][0]);
            a1[0][1] = fmaf(wv.x, xv.y, a1[0][1]);
            a1[0][2] = fmaf(wv.x, xv.z, a1[0][2]);
            a1[0][3] = fmaf(wv.x, xv.w, a1[0][3]);
            a1[1][0] = fmaf(wv.y, xv.x, a1[1][0]);
            a1[1][1] = fmaf(wv.y, xv.y, a1[1][1]);
            a1[1][2] = fmaf(wv.y, xv.z, a1[1][2]);
            a1[1][3] = fmaf(wv.y, xv.w, a1[1][3]);
        }
    }
    #pragma unroll
    for (int j = 0; j < 4; ++j) {
        hs[ml * 20 + pg * 4 + j]       = a1[0][j] + b1a;
        hs[(ml + 1) * 20 + pg * 4 + j] = a1[1][j] + b1b;
    }
    __syncthreads();

    // ---- GEMM2: x_[c=t][p], sequential fp32 FMA chain over m ascending ----
    // Weights software-pipelined; hs rows are wave-uniform broadcasts.
    const float b2v = b2[t];
    float a2[TP];
    #pragma unroll
    for (int j = 0; j < TP; ++j) a2[j] = 0.f;

    float w2b[2][16];
    #pragma unroll
    for (int k = 0; k < 16; ++k)
        w2b[0][k] = w2t[k * CIN + t];

    #pragma unroll
    for (int ch = 0; ch < 8; ++ch) {
        const int cur = ch & 1;
        if (ch < 7) {
            #pragma unroll
            for (int k = 0; k < 16; ++k)
                w2b[cur ^ 1][k] = w2t[((ch + 1) * 16 + k) * CIN + t];
        }
        #pragma unroll
        for (int k = 0; k < 16; ++k) {
            const float wv = w2b[cur][k];
            const float* hr = &hs[(ch * 16 + k) * 20];     // wave-uniform broadcast row
            #pragma unroll
            for (int j = 0; j < TP; ++j)
                a2[j] = fmaf(wv, hr[j], a2[j]);
        }
    }
    float xv32[TP];
    #pragma unroll
    for (int j = 0; j < TP; ++j)
        xv32[j] = a2[j] + b2v;
    __syncthreads();   // all hs reads complete before s_arr overwrite

    // ---- sigmoid bits -> s_arr; prod = x * x_ in-place over xs (row t exclusive) ----
    {
        const int slot = t + (t >> 4);
        #pragma unroll
        for (int p2 = 0; p2 < TP; ++p2) {
#pragma clang fp contract(off)
            const float e = numpy_expf(-xv32[p2]);
            const float d = 1.0f + e;
            const float s = 1.0f / d;
            s_arr[p2 * SROW + slot] = __float_as_uint(s);
            xs[t * 20 + p2] = xs[t * 20 + p2] * xv32[p2];
        }
    }
    __syncthreads();

    // ---- bitonic sort: pixel group = 16 lanes (wave-local, no barriers) ----
    const int p   = t >> 4;
    const int l16 = t & 15;

    u64 k[16];
    {
        const u32* sp = &s_arr[p * SROW + l16 * 17];   // 16 consecutive u32, conflict-free
        const int cbase = l16 * 16;
        #pragma unroll
        for (int r = 0; r < 16; ++r) {
            const u64 s = (u64)sp[r];
            k[r] = (s << 8) | (u64)(255 - (cbase + r));
        }
    }

    // stages 1..3: compile-time directions, intra-lane
    intra_ct<1, 1>(k);
    intra_ct<2, 2>(k); intra_ct<1, 2>(k);
    intra_ct<4, 3>(k); intra_ct<2, 3>(k); intra_ct<1, 3>(k);
    // stage 4: dir = bit4 of e = l16&1, intra-lane
    {
        const bool dsc = (l16 & 1) != 0;
        intra_rt<8>(k, dsc); intra_rt<4>(k, dsc); intra_rt<2>(k, dsc); intra_rt<1>(k, dsc);
    }
    // stage 5: cross m=1 then intra 8..1
    {
        const bool dsc = ((l16 >> 1) & 1) != 0;
        cross_rt<1, 0x041F>(k, l16, dsc);
        intra_rt<8>(k, dsc); intra_rt<4>(k, dsc); intra_rt<2>(k, dsc); intra_rt<1>(k, dsc);
    }
    // stage 6: cross m=2,1 then intra
    {
        const bool dsc = ((l16 >> 2) & 1) != 0;
        cross_rt<2, 0x081F>(k, l16, dsc);
        cross_rt<1, 0x041F>(k, l16, dsc);
        intra_rt<8>(k, dsc); intra_rt<4>(k, dsc); intra_rt<2>(k, dsc); intra_rt<1>(k, dsc);
    }
    // stage 7: cross m=4,2,1 then intra
    {
        const bool dsc = ((l16 >> 3) & 1) != 0;
        cross_rt<4, 0x101F>(k, l16, dsc);
        cross_rt<2, 0x081F>(k, l16, dsc);
        cross_rt<1, 0x041F>(k, l16, dsc);
        intra_rt<8>(k, dsc); intra_rt<4>(k, dsc); intra_rt<2>(k, dsc); intra_rt<1>(k, dsc);
    }
    // stage 8 (final, ascending): cross m=8,4,2,1 then intra
    {
        cross_rt<8, 0x201F>(k, l16, false);
        cross_rt<4, 0x101F>(k, l16, false);
        cross_rt<2, 0x081F>(k, l16, false);
        cross_rt<1, 0x041F>(k, l16, false);
        intra_rt<8>(k, false); intra_rt<4>(k, false); intra_rt<2>(k, false); intra_rt<1>(k, false);
    }

    // ---- epilogue: positions e=128..255 hold ranks 127..0 ----
    if (l16 >= 8) {
        const int rbase = 255 - l16 * 16;    // rank = rbase - r
        float* ob = out + (size_t)b * KOUT * HWSZ + hw0 + p;
        #pragma unroll
        for (int r = 0; r < 16; ++r) {
            const int c = 255 - (int)(k[r] & 0xFF);
            ob[(size_t)(rbase - r) * HWSZ] = xs[c * 20 + p];
        }
    }
}

extern "C" void kernel_launch(void* const* d_in, const int* in_sizes, int n_in,
                              void* d_out, int out_size, void* d_ws, size_t ws_size,
                              hipStream_t stream) {
    const float* x  = (const float*)d_in[0];
    const float* w1 = (const float*)d_in[1];
    const float* b1 = (const float*)d_in[2];
    const float* w2 = (const float*)d_in[3];
    const float* b2 = (const float*)d_in[4];

    float* w1t = (float*)d_ws;              // 128 KB
    float* w2t = w1t + CIN * MEDC;          // 128 KB

    prep_T<<<CIN, MEDC, 0, stream>>>(w1, w2, w1t, w2t);
    csel_main<<<(NB * HWSZ) / TP, 256, 0, stream>>>(x, w1t, w2t, b1, b2, (float*)d_out);
}